// Round 1
// baseline (1908.074 us; speedup 1.0000x reference)
//
#include <hip/hip_runtime.h>

#define FIN 1433
#define F1 30
#define F2 10
#define F3 7

// ---------------------------------------------------------------------------
// CSR build: histogram of dst, prefix scan, scatter edges by dst
// ---------------------------------------------------------------------------

__global__ __launch_bounds__(256) void hist_kernel(const int* __restrict__ dst,
                                                   int* __restrict__ ecnt, int E) {
    int i = blockIdx.x * blockDim.x + threadIdx.x;
    if (i < E) atomicAdd(&ecnt[dst[i]], 1);
}

// Phase A: per-block (1024 elems) sums
__global__ __launch_bounds__(256) void scanA(const int* __restrict__ ecnt,
                                             int* __restrict__ bsum, int N) {
    __shared__ int ws[4];
    int base = blockIdx.x * 1024 + threadIdx.x * 4;
    int s = 0;
#pragma unroll
    for (int m = 0; m < 4; ++m) { int idx = base + m; if (idx < N) s += ecnt[idx]; }
    for (int o = 1; o < 64; o <<= 1) s += __shfl_xor(s, o, 64);
    int lane = threadIdx.x & 63, wid = threadIdx.x >> 6;
    if (lane == 0) ws[wid] = s;
    __syncthreads();
    if (threadIdx.x == 0) bsum[blockIdx.x] = ws[0] + ws[1] + ws[2] + ws[3];
}

// Phase B: scan the (<=128) block sums; 1 block of 128 threads
__global__ __launch_bounds__(128) void scanB(const int* __restrict__ bsum,
                                             int* __restrict__ boff,
                                             int* __restrict__ rowptr, int NB, int N) {
    __shared__ int wtot[2];
    int t = threadIdx.x;
    int v = (t < NB) ? bsum[t] : 0;
    int lane = t & 63, w = t >> 6;
    int incl = v;
    for (int o = 1; o < 64; o <<= 1) { int u = __shfl_up(incl, o, 64); if (lane >= o) incl += u; }
    if (lane == 63) wtot[w] = incl;
    __syncthreads();
    int offw = (w == 1) ? wtot[0] : 0;
    if (t < NB) boff[t] = offw + incl - v;
    if (t == 127) rowptr[N] = wtot[0] + wtot[1];
}

// Phase C: block-local exclusive scan + global offset -> rowptr
__global__ __launch_bounds__(256) void scanC(const int* __restrict__ ecnt,
                                             const int* __restrict__ boff,
                                             int* __restrict__ rowptr, int N) {
    __shared__ int wsum[4];
    int t = threadIdx.x;
    int base = blockIdx.x * 1024 + t * 4;
    int v[4]; int s = 0;
#pragma unroll
    for (int m = 0; m < 4; ++m) { int idx = base + m; v[m] = (idx < N) ? ecnt[idx] : 0; s += v[m]; }
    int lane = t & 63, wid = t >> 6;
    int incl = s;
    for (int o = 1; o < 64; o <<= 1) { int u = __shfl_up(incl, o, 64); if (lane >= o) incl += u; }
    if (lane == 63) wsum[wid] = incl;
    __syncthreads();
    int woff = 0;
    for (int w = 0; w < wid; ++w) woff += wsum[w];
    int run = boff[blockIdx.x] + woff + (incl - s);
#pragma unroll
    for (int m = 0; m < 4; ++m) { int idx = base + m; if (idx < N) rowptr[idx] = run; run += v[m]; }
}

__global__ __launch_bounds__(256) void scatter_kernel(const int* __restrict__ src,
                                                      const int* __restrict__ dst,
                                                      const int* __restrict__ rowptr,
                                                      int* __restrict__ cursor,
                                                      int* __restrict__ col, int E) {
    int i = blockIdx.x * blockDim.x + threadIdx.x;
    if (i < E) {
        int d = dst[i];
        int pos = rowptr[d] + atomicAdd(&cursor[d], 1);
        col[pos] = src[i];
    }
}

__global__ __launch_bounds__(256) void isd_kernel(const int* __restrict__ ecnt,
                                                  float* __restrict__ isd, int N) {
    int i = blockIdx.x * blockDim.x + threadIdx.x;
    if (i < N) isd[i] = rsqrtf((float)(ecnt[i] + 1));   // +1 = self-loop; deg>=1 always
}

// ---------------------------------------------------------------------------
// Layer-1 GEMM: hw1[N,30] = x[N,1433] @ W1[1433,30]
// 256 rows/block (thread-per-row); x tile staged in LDS (stride 33 -> 2-way = free);
// W row reads are wave-uniform -> scalar loads. Coalesced store via LDS transpose.
// ---------------------------------------------------------------------------
__global__ __launch_bounds__(256) void gemm1_kernel(const float* __restrict__ x,
                                                    const float* __restrict__ W,
                                                    float* __restrict__ hw, int N) {
    __shared__ float xs[256 * 33];
    const int t = threadIdx.x;
    const int row0 = blockIdx.x * 256;
    float acc[F1];
#pragma unroll
    for (int j = 0; j < F1; ++j) acc[j] = 0.f;

    for (int k0 = 0; k0 < FIN; k0 += 32) {
        const int kc = min(32, FIN - k0);
        __syncthreads();
#pragma unroll
        for (int it = 0; it < 32; ++it) {
            int idx = t + it * 256;
            int r = idx >> 5, k = idx & 31;
            int rr = row0 + r;
            float vv = 0.f;
            if (k < kc && rr < N) vv = x[(long long)rr * FIN + k0 + k];
            xs[r * 33 + k] = vv;
        }
        __syncthreads();
#pragma unroll 8
        for (int k = 0; k < kc; ++k) {
            float xv = xs[t * 33 + k];
            const float* wr = &W[(k0 + k) * F1];
#pragma unroll
            for (int j = 0; j < F1; ++j) acc[j] = fmaf(xv, wr[j], acc[j]);
        }
    }

    // coalesced store: acc -> LDS (stride 31) -> contiguous 256x30 global tile
    __syncthreads();
#pragma unroll
    for (int j = 0; j < F1; ++j) xs[t * 31 + j] = acc[j];
    __syncthreads();
    for (int idx = t; idx < 256 * F1; idx += 256) {
        int r = idx / F1, j = idx - r * F1;
        if (row0 + r < N) hw[(long long)row0 * F1 + idx] = xs[r * 31 + j];
    }
}

// ---------------------------------------------------------------------------
// Small dense transforms (wave-uniform W -> scalar loads)
// ---------------------------------------------------------------------------
template <int FI, int FO>
__global__ __launch_bounds__(256) void gemm_small(const float* __restrict__ h,
                                                  const float* __restrict__ W,
                                                  float* __restrict__ out, int N) {
    int i = blockIdx.x * blockDim.x + threadIdx.x;
    if (i >= N) return;
    float hv[FI];
#pragma unroll
    for (int k = 0; k < FI; ++k) hv[k] = h[(long long)i * FI + k];
#pragma unroll
    for (int j = 0; j < FO; ++j) {
        float a = 0.f;
#pragma unroll
        for (int k = 0; k < FI; ++k) a = fmaf(hv[k], W[k * FO + j], a);
        out[(long long)i * FO + j] = a;
    }
}

// ---------------------------------------------------------------------------
// Propagation: per-node gather over CSR. Sub-wave of S lanes per node, lane=feature.
// agg[n] = is[n] * ( sum_src is[src]*hw[src] + is[n]*hw[n] )
// EPI: 1 = +bias,relu   2 = +bias,log_softmax
// ---------------------------------------------------------------------------
template <int S, int F, int EPI>
__global__ __launch_bounds__(256) void prop_kernel(const float* __restrict__ hw,
                                                   const float* __restrict__ isd,
                                                   const int* __restrict__ rowptr,
                                                   const int* __restrict__ col,
                                                   const float* __restrict__ bias,
                                                   float* __restrict__ out, int N) {
    const int NPB = 256 / S;
    int lane = threadIdx.x & 63;
    int li = lane & (S - 1);
    int seg = lane / S;
    int wid = threadIdx.x >> 6;
    long long node = (long long)blockIdx.x * NPB + wid * (64 / S) + seg;
    if (node >= N) return;                       // uniform within each S-lane segment

    float mis = isd[node];
    float acc = 0.f;
    if (li < F) acc = mis * hw[node * F + li];   // self-loop term
    int s0 = rowptr[node], s1 = rowptr[node + 1];
    for (int e0 = s0; e0 < s1; e0 += S) {
        int e = e0 + li;
        int sv = (e < s1) ? col[e] : 0;
        int cnt = min(S, s1 - e0);
        for (int i = 0; i < cnt; ++i) {
            int sj = __shfl(sv, i, S);           // segment-local broadcast
            float w = isd[sj];
            if (li < F) acc = fmaf(w, hw[(long long)sj * F + li], acc);
        }
    }
    acc *= mis;

    if (EPI == 1) {
        if (li < F) out[node * F + li] = fmaxf(acc + bias[li], 0.f);
    } else {  // log_softmax over F values held across the segment
        float v = (li < F) ? (acc + bias[li]) : -1e30f;
        float m = v;
#pragma unroll
        for (int o = S / 2; o >= 1; o >>= 1) m = fmaxf(m, __shfl_xor(m, o, S));
        float ex = (li < F) ? expf(v - m) : 0.f;
        float ss = ex;
#pragma unroll
        for (int o = S / 2; o >= 1; o >>= 1) ss += __shfl_xor(ss, o, S);
        if (li < F) out[node * F + li] = (v - m) - logf(ss);
    }
}

// ---------------------------------------------------------------------------

extern "C" void kernel_launch(void* const* d_in, const int* in_sizes, int n_in,
                              void* d_out, int out_size, void* d_ws, size_t ws_size,
                              hipStream_t stream) {
    const float* x  = (const float*)d_in[0];
    const int*   ei = (const int*)d_in[1];
    const float* W1 = (const float*)d_in[2];
    const float* b1 = (const float*)d_in[3];
    const float* W2 = (const float*)d_in[4];
    const float* b2 = (const float*)d_in[5];
    const float* W3 = (const float*)d_in[6];
    const float* b3 = (const float*)d_in[7];
    float* out = (float*)d_out;

    const int N = in_sizes[0] / FIN;
    const int E = in_sizes[1] / 2;
    const int* esrc = ei;
    const int* edst = ei + E;

    char* ws = (char*)d_ws;
    size_t off = 0;
    auto alloc = [&](size_t bytes) -> void* {
        void* p = ws + off;
        off += (bytes + 511) & ~(size_t)511;
        return p;
    };
    int NB = (N + 1023) / 1024;
    int*   ecnt   = (int*)alloc((size_t)N * 4);
    int*   cursor = (int*)alloc((size_t)N * 4);
    int*   rowptr = (int*)alloc((size_t)(N + 1) * 4);
    int*   bsum   = (int*)alloc((size_t)NB * 4);
    int*   boff   = (int*)alloc((size_t)NB * 4);
    float* isd    = (float*)alloc((size_t)N * 4);
    int*   col    = (int*)alloc((size_t)E * 4);
    float* hw1    = (float*)alloc((size_t)N * F1 * 4);
    float* h1     = (float*)alloc((size_t)N * F1 * 4);
    float* hw2    = (float*)alloc((size_t)N * F2 * 4);
    float* h2     = (float*)alloc((size_t)N * F2 * 4);
    float* hw3    = (float*)alloc((size_t)N * F3 * 4);

    hipMemsetAsync(ecnt,   0, (size_t)N * 4, stream);
    hipMemsetAsync(cursor, 0, (size_t)N * 4, stream);

    int eb = (E + 255) / 256;
    hist_kernel<<<eb, 256, 0, stream>>>(edst, ecnt, E);
    scanA<<<NB, 256, 0, stream>>>(ecnt, bsum, N);
    scanB<<<1, 128, 0, stream>>>(bsum, boff, rowptr, NB, N);
    scanC<<<NB, 256, 0, stream>>>(ecnt, boff, rowptr, N);
    scatter_kernel<<<eb, 256, 0, stream>>>(esrc, edst, rowptr, cursor, col, E);
    isd_kernel<<<(N + 255) / 256, 256, 0, stream>>>(ecnt, isd, N);

    gemm1_kernel<<<(N + 255) / 256, 256, 0, stream>>>(x, W1, hw1, N);
    prop_kernel<32, F1, 1><<<(N + 7) / 8, 256, 0, stream>>>(hw1, isd, rowptr, col, b1, h1, N);
    gemm_small<F1, F2><<<(N + 255) / 256, 256, 0, stream>>>(h1, W2, hw2, N);
    prop_kernel<16, F2, 1><<<(N + 15) / 16, 256, 0, stream>>>(hw2, isd, rowptr, col, b2, h2, N);
    gemm_small<F2, F3><<<(N + 255) / 256, 256, 0, stream>>>(h2, W3, hw3, N);
    prop_kernel<8, F3, 2><<<(N + 31) / 32, 256, 0, stream>>>(hw3, isd, rowptr, col, b3, out, N);
}

// Round 2
// 1510.122 us; speedup vs baseline: 1.2635x; 1.2635x over previous
//
#include <hip/hip_runtime.h>
#include <hip/hip_bf16.h>

#define FIN 1433
#define F1 30
#define F2 10
#define F3 7

typedef __attribute__((ext_vector_type(8))) short short8v;
typedef __attribute__((ext_vector_type(4))) float f32x4;

// ---------------------------------------------------------------------------
// CSR build: histogram of dst, prefix scan, scatter edges by dst
// ---------------------------------------------------------------------------

__global__ __launch_bounds__(256) void hist_kernel(const int* __restrict__ dst,
                                                   int* __restrict__ ecnt, int E) {
    int i = blockIdx.x * blockDim.x + threadIdx.x;
    if (i < E) atomicAdd(&ecnt[dst[i]], 1);
}

__global__ __launch_bounds__(256) void scanA(const int* __restrict__ ecnt,
                                             int* __restrict__ bsum, int N) {
    __shared__ int ws[4];
    int base = blockIdx.x * 1024 + threadIdx.x * 4;
    int s = 0;
#pragma unroll
    for (int m = 0; m < 4; ++m) { int idx = base + m; if (idx < N) s += ecnt[idx]; }
    for (int o = 1; o < 64; o <<= 1) s += __shfl_xor(s, o, 64);
    int lane = threadIdx.x & 63, wid = threadIdx.x >> 6;
    if (lane == 0) ws[wid] = s;
    __syncthreads();
    if (threadIdx.x == 0) bsum[blockIdx.x] = ws[0] + ws[1] + ws[2] + ws[3];
}

__global__ __launch_bounds__(128) void scanB(const int* __restrict__ bsum,
                                             int* __restrict__ boff,
                                             int* __restrict__ rowptr, int NB, int N) {
    __shared__ int wtot[2];
    int t = threadIdx.x;
    int v = (t < NB) ? bsum[t] : 0;
    int lane = t & 63, w = t >> 6;
    int incl = v;
    for (int o = 1; o < 64; o <<= 1) { int u = __shfl_up(incl, o, 64); if (lane >= o) incl += u; }
    if (lane == 63) wtot[w] = incl;
    __syncthreads();
    int offw = (w == 1) ? wtot[0] : 0;
    if (t < NB) boff[t] = offw + incl - v;
    if (t == 127) rowptr[N] = wtot[0] + wtot[1];
}

// block-local exclusive scan + global offset -> rowptr, cursor init, isd
__global__ __launch_bounds__(256) void scanC(const int* __restrict__ ecnt,
                                             const int* __restrict__ boff,
                                             int* __restrict__ rowptr,
                                             int* __restrict__ cursor,
                                             float* __restrict__ isd, int N) {
    __shared__ int wsum[4];
    int t = threadIdx.x;
    int base = blockIdx.x * 1024 + t * 4;
    int v[4]; int s = 0;
#pragma unroll
    for (int m = 0; m < 4; ++m) { int idx = base + m; v[m] = (idx < N) ? ecnt[idx] : 0; s += v[m]; }
    int lane = t & 63, wid = t >> 6;
    int incl = s;
    for (int o = 1; o < 64; o <<= 1) { int u = __shfl_up(incl, o, 64); if (lane >= o) incl += u; }
    if (lane == 63) wsum[wid] = incl;
    __syncthreads();
    int woff = 0;
    for (int w = 0; w < wid; ++w) woff += wsum[w];
    int run = boff[blockIdx.x] + woff + (incl - s);
#pragma unroll
    for (int m = 0; m < 4; ++m) {
        int idx = base + m;
        if (idx < N) {
            rowptr[idx] = run;
            cursor[idx] = run;
            isd[idx] = rsqrtf((float)(v[m] + 1));   // +1 self-loop, deg >= 1 always
        }
        run += v[m];
    }
}

__global__ __launch_bounds__(256) void scatter_kernel(const int* __restrict__ src,
                                                      const int* __restrict__ dst,
                                                      int* __restrict__ cursor,
                                                      int* __restrict__ col, int E) {
    int i = blockIdx.x * blockDim.x + threadIdx.x;
    if (i < E) {
        int pos = atomicAdd(&cursor[dst[i]], 1);
        col[pos] = src[i];
    }
}

// ---------------------------------------------------------------------------
// Layer-1 GEMM (bf16 MFMA): hw[r][j] = isd[r] * sum_k x[r][k] * W[k][j]
// 128 rows/block, 4 waves, each wave owns 32 rows (2 M-frags x 2 N-frags).
// A staged f32->bf16 in LDS, row stride 40 bf16 (80 B -> 2-way bank alias = free).
// B staged transposed (Bt[n][k]) so fragments are contiguous ds_read_b128.
// Fragment layout (m89/m92-verified): a[j]=A[l&15][(l>>4)*8+j],
// b[j]=B[(l>>4)*8+j][l&15], D: col=l&15, row=(l>>4)*4+reg.
// ---------------------------------------------------------------------------
__global__ __launch_bounds__(256) void gemm1_mfma(const float* __restrict__ x,
                                                  const float* __restrict__ W,
                                                  const float* __restrict__ isd,
                                                  float* __restrict__ hw, int N) {
    __shared__ __hip_bfloat16 A_lds[128 * 40];
    __shared__ __hip_bfloat16 B_lds[32 * 40];
    const int t = threadIdx.x;
    const int lane = t & 63;
    const int wv = t >> 6;
    const int row0 = blockIdx.x * 128;

    f32x4 acc[2][2] = {};

    for (int k0 = 0; k0 < FIN; k0 += 32) {
        const int kc = min(32, FIN - k0);
        __syncthreads();
        // stage A: 128 rows x 32 k as bf16 pairs (consecutive 16 threads = 1 row)
#pragma unroll
        for (int i = 0; i < 8; ++i) {
            int pid = t + i * 256;            // 0..2047
            int r = pid >> 4, kp = pid & 15;
            int rr = row0 + r;
            float a0 = 0.f, a1 = 0.f;
            if (rr < N) {
                int k = 2 * kp;
                const float* xp = &x[(long long)rr * FIN + k0 + k];
                if (k < kc)     a0 = xp[0];
                if (k + 1 < kc) a1 = xp[1];
            }
            *(__hip_bfloat162*)&A_lds[r * 40 + 2 * kp] =
                __float22bfloat162_rn(make_float2(a0, a1));
        }
        // stage B transposed: Bt[j][k], zero-padded to 32x32
#pragma unroll
        for (int i = 0; i < 4; ++i) {
            int e = t + i * 256;              // 0..1023
            int k = e >> 5, j = e & 31;
            float v = (j < F1 && k < kc) ? W[(k0 + k) * F1 + j] : 0.f;
            B_lds[j * 40 + k] = __float2bfloat16(v);
        }
        __syncthreads();

        const char* Ab = (const char*)A_lds;
        const char* Bb = (const char*)B_lds;
        short8v afr[2], bfr[2];
#pragma unroll
        for (int m = 0; m < 2; ++m) {
            int r = wv * 32 + m * 16 + (lane & 15);
            afr[m] = *(const short8v*)(Ab + r * 80 + (lane >> 4) * 16);
        }
#pragma unroll
        for (int n = 0; n < 2; ++n) {
            int c = n * 16 + (lane & 15);
            bfr[n] = *(const short8v*)(Bb + c * 80 + (lane >> 4) * 16);
        }
#pragma unroll
        for (int m = 0; m < 2; ++m)
#pragma unroll
            for (int n = 0; n < 2; ++n)
                acc[m][n] = __builtin_amdgcn_mfma_f32_16x16x32_bf16(
                    afr[m], bfr[n], acc[m][n], 0, 0, 0);
    }

    // epilogue: scale row by isd, store cols < 30
#pragma unroll
    for (int m = 0; m < 2; ++m) {
#pragma unroll
        for (int r = 0; r < 4; ++r) {
            int grow = row0 + wv * 32 + m * 16 + (lane >> 4) * 4 + r;
            if (grow < N) {
                float s = isd[grow];
#pragma unroll
                for (int n = 0; n < 2; ++n) {
                    int colj = n * 16 + (lane & 15);
                    if (colj < F1) hw[(long long)grow * F1 + colj] = s * acc[m][n][r];
                }
            }
        }
    }
}

// ---------------------------------------------------------------------------
// Small dense transforms, isd folded into the store
// ---------------------------------------------------------------------------
template <int FI, int FO>
__global__ __launch_bounds__(256) void gemm_small(const float* __restrict__ h,
                                                  const float* __restrict__ W,
                                                  const float* __restrict__ isd,
                                                  float* __restrict__ out, int N) {
    int i = blockIdx.x * blockDim.x + threadIdx.x;
    if (i >= N) return;
    float hv[FI];
#pragma unroll
    for (int k = 0; k < FI; ++k) hv[k] = h[(long long)i * FI + k];
    float s = isd[i];
#pragma unroll
    for (int j = 0; j < FO; ++j) {
        float a = 0.f;
#pragma unroll
        for (int k = 0; k < FI; ++k) a = fmaf(hv[k], W[k * FO + j], a);
        out[(long long)i * FO + j] = s * a;
    }
}

// ---------------------------------------------------------------------------
// Propagation over CSR. One 64-lane wave per node; R = 64/S replicas each
// process one edge per step (lane = feature within replica). hws rows are
// pre-scaled by isd[src], so per edge it's a pure gather+add.
// out = EPI( isd[node] * (sum_src hws[src] + hws[node]) + bias )
// EPI: 1 = relu   2 = log_softmax
// ---------------------------------------------------------------------------
template <int S, int F, int EPI>
__global__ __launch_bounds__(256) void prop_kernel(const float* __restrict__ hws,
                                                   const float* __restrict__ isd,
                                                   const int* __restrict__ rowptr,
                                                   const int* __restrict__ col,
                                                   const float* __restrict__ bias,
                                                   float* __restrict__ out, int N) {
    const int R = 64 / S;
    int lane = threadIdx.x & 63;
    int li = lane & (S - 1);
    int p = lane / S;                       // replica id
    int wid = threadIdx.x >> 6;
    long long node = (long long)blockIdx.x * 4 + wid;
    if (node >= N) return;

    float acc = (p == 0 && li < F) ? hws[node * F + li] : 0.f;   // self-loop
    int s0 = rowptr[node], s1 = rowptr[node + 1];
    for (int e0 = s0; e0 < s1; e0 += 64) {
        int e = e0 + lane;
        int ev = (e < s1) ? col[e] : 0;
        int cnt = min(64, s1 - e0);
        for (int i = 0; i * R < cnt; ++i) {
            int idx = i * R + p;
            int sj = __shfl(ev, idx, 64);
            if (idx < cnt && li < F) acc += hws[(long long)sj * F + li];
        }
    }
    // reduce replicas (after this every lane holds the feature-li total)
#pragma unroll
    for (int o = 32; o >= S; o >>= 1) acc += __shfl_xor(acc, o, 64);

    float v = isd[node] * acc + ((li < F) ? bias[li] : 0.f);
    if (EPI == 1) {
        if (p == 0 && li < F) out[node * F + li] = fmaxf(v, 0.f);
    } else {
        float vv = (li < F) ? v : -1e30f;
        float m = vv;
#pragma unroll
        for (int o = S / 2; o >= 1; o >>= 1) m = fmaxf(m, __shfl_xor(m, o, S));
        float ex = (li < F) ? __expf(vv - m) : 0.f;
        float ss = ex;
#pragma unroll
        for (int o = S / 2; o >= 1; o >>= 1) ss += __shfl_xor(ss, o, S);
        if (p == 0 && li < F) out[node * F + li] = (vv - m) - __logf(ss);
    }
}

// ---------------------------------------------------------------------------

extern "C" void kernel_launch(void* const* d_in, const int* in_sizes, int n_in,
                              void* d_out, int out_size, void* d_ws, size_t ws_size,
                              hipStream_t stream) {
    const float* x  = (const float*)d_in[0];
    const int*   ei = (const int*)d_in[1];
    const float* W1 = (const float*)d_in[2];
    const float* b1 = (const float*)d_in[3];
    const float* W2 = (const float*)d_in[4];
    const float* b2 = (const float*)d_in[5];
    const float* W3 = (const float*)d_in[6];
    const float* b3 = (const float*)d_in[7];
    float* out = (float*)d_out;

    const int N = in_sizes[0] / FIN;
    const int E = in_sizes[1] / 2;
    const int* esrc = ei;
    const int* edst = ei + E;

    char* ws = (char*)d_ws;
    size_t off = 0;
    auto alloc = [&](size_t bytes) -> void* {
        void* p = ws + off;
        off += (bytes + 511) & ~(size_t)511;
        return p;
    };
    int NB = (N + 1023) / 1024;
    int*   ecnt   = (int*)alloc((size_t)N * 4);
    int*   cursor = (int*)alloc((size_t)N * 4);
    int*   rowptr = (int*)alloc((size_t)(N + 1) * 4);
    int*   bsum   = (int*)alloc((size_t)NB * 4);
    int*   boff   = (int*)alloc((size_t)NB * 4);
    float* isd    = (float*)alloc((size_t)N * 4);
    int*   col    = (int*)alloc((size_t)E * 4);
    float* hw1    = (float*)alloc((size_t)N * F1 * 4);
    float* h1     = (float*)alloc((size_t)N * F1 * 4);
    float* hw2    = (float*)alloc((size_t)N * F2 * 4);
    float* h2     = (float*)alloc((size_t)N * F2 * 4);
    float* hw3    = (float*)alloc((size_t)N * F3 * 4);

    hipMemsetAsync(ecnt, 0, (size_t)N * 4, stream);

    int eb = (E + 255) / 256;
    hist_kernel<<<eb, 256, 0, stream>>>(edst, ecnt, E);
    scanA<<<NB, 256, 0, stream>>>(ecnt, bsum, N);
    scanB<<<1, 128, 0, stream>>>(bsum, boff, rowptr, NB, N);
    scanC<<<NB, 256, 0, stream>>>(ecnt, boff, rowptr, cursor, isd, N);
    scatter_kernel<<<eb, 256, 0, stream>>>(esrc, edst, cursor, col, E);

    gemm1_mfma<<<(N + 127) / 128, 256, 0, stream>>>(x, W1, isd, hw1, N);
    prop_kernel<32, F1, 1><<<(N + 3) / 4, 256, 0, stream>>>(hw1, isd, rowptr, col, b1, h1, N);
    gemm_small<F1, F2><<<(N + 255) / 256, 256, 0, stream>>>(h1, W2, isd, hw2, N);
    prop_kernel<16, F2, 1><<<(N + 3) / 4, 256, 0, stream>>>(hw2, isd, rowptr, col, b2, h2, N);
    gemm_small<F2, F3><<<(N + 255) / 256, 256, 0, stream>>>(h2, W3, isd, hw3, N);
    prop_kernel<8, F3, 2><<<(N + 3) / 4, 256, 0, stream>>>(hw3, isd, rowptr, col, b3, out, N);
}

// Round 5
// 1410.381 us; speedup vs baseline: 1.3529x; 1.0707x over previous
//
#include <hip/hip_runtime.h>
#include <hip/hip_bf16.h>

#define FIN 1433
#define F1 30
#define F2 10
#define F3 7
#define S1 32   // padded row strides (floats)
#define S2 12
#define S3 8
#define WTK 1440  // 45*32, zero-padded K for Wt

typedef __attribute__((ext_vector_type(8))) short short8v;
typedef __attribute__((ext_vector_type(4))) float f32x4;

static __device__ inline short bf16b(float v) {
    union { __hip_bfloat16 h; unsigned short u; } cv;
    cv.h = __float2bfloat16(v);
    return (short)cv.u;
}

// ---------------------------------------------------------------------------
// CSR build: histogram of dst, prefix scan, scatter edges by dst
// ---------------------------------------------------------------------------

__global__ __launch_bounds__(256) void hist_kernel(const int* __restrict__ dst,
                                                   int* __restrict__ ecnt, int E) {
    int i = blockIdx.x * blockDim.x + threadIdx.x;
    if (i < E) atomicAdd(&ecnt[dst[i]], 1);
}

__global__ __launch_bounds__(256) void scanA(const int* __restrict__ ecnt,
                                             int* __restrict__ bsum, int N) {
    __shared__ int ws[4];
    int base = blockIdx.x * 1024 + threadIdx.x * 4;
    int s = 0;
#pragma unroll
    for (int m = 0; m < 4; ++m) { int idx = base + m; if (idx < N) s += ecnt[idx]; }
    for (int o = 1; o < 64; o <<= 1) s += __shfl_xor(s, o, 64);
    int lane = threadIdx.x & 63, wid = threadIdx.x >> 6;
    if (lane == 0) ws[wid] = s;
    __syncthreads();
    if (threadIdx.x == 0) bsum[blockIdx.x] = ws[0] + ws[1] + ws[2] + ws[3];
}

__global__ __launch_bounds__(128) void scanB(const int* __restrict__ bsum,
                                             int* __restrict__ boff,
                                             int* __restrict__ rowptr, int NB, int N) {
    __shared__ int wtot[2];
    int t = threadIdx.x;
    int v = (t < NB) ? bsum[t] : 0;
    int lane = t & 63, w = t >> 6;
    int incl = v;
    for (int o = 1; o < 64; o <<= 1) { int u = __shfl_up(incl, o, 64); if (lane >= o) incl += u; }
    if (lane == 63) wtot[w] = incl;
    __syncthreads();
    int offw = (w == 1) ? wtot[0] : 0;
    if (t < NB) boff[t] = offw + incl - v;
    if (t == 127) rowptr[N] = wtot[0] + wtot[1];
}

// block-local exclusive scan + global offset -> rowptr, cursor init, isd
__global__ __launch_bounds__(256) void scanC(const int* __restrict__ ecnt,
                                             const int* __restrict__ boff,
                                             int* __restrict__ rowptr,
                                             int* __restrict__ cursor,
                                             float* __restrict__ isd, int N) {
    __shared__ int wsum[4];
    int t = threadIdx.x;
    int base = blockIdx.x * 1024 + t * 4;
    int v[4]; int s = 0;
#pragma unroll
    for (int m = 0; m < 4; ++m) { int idx = base + m; v[m] = (idx < N) ? ecnt[idx] : 0; s += v[m]; }
    int lane = t & 63, wid = t >> 6;
    int incl = s;
    for (int o = 1; o < 64; o <<= 1) { int u = __shfl_up(incl, o, 64); if (lane >= o) incl += u; }
    if (lane == 63) wsum[wid] = incl;
    __syncthreads();
    int woff = 0;
    for (int w = 0; w < wid; ++w) woff += wsum[w];
    int run = boff[blockIdx.x] + woff + (incl - s);
#pragma unroll
    for (int m = 0; m < 4; ++m) {
        int idx = base + m;
        if (idx < N) {
            rowptr[idx] = run;
            cursor[idx] = run;
            isd[idx] = rsqrtf((float)(v[m] + 1));   // +1 self-loop, deg >= 1 always
        }
        run += v[m];
    }
}

__global__ __launch_bounds__(256) void scatter_kernel(const int* __restrict__ src,
                                                      const int* __restrict__ dst,
                                                      int* __restrict__ cursor,
                                                      int* __restrict__ col, int E) {
    int i = blockIdx.x * blockDim.x + threadIdx.x;
    if (i < E) {
        int pos = atomicAdd(&cursor[dst[i]], 1);
        col[pos] = src[i];
    }
}

// ---------------------------------------------------------------------------
// W1 -> bf16, transposed + zero-padded: Wt[32][WTK], Wt[j][k] = W1[k][j]
// ---------------------------------------------------------------------------
__global__ __launch_bounds__(256) void wt_prep(const float* __restrict__ W,
                                               __hip_bfloat16* __restrict__ Wt) {
    int idx = blockIdx.x * 256 + threadIdx.x;
    if (idx >= 32 * WTK) return;
    int j = idx / WTK, k = idx - j * WTK;
    float v = (j < F1 && k < FIN) ? W[k * F1 + j] : 0.f;
    Wt[idx] = __float2bfloat16(v);
}

// ---------------------------------------------------------------------------
// Layer-1 GEMM (bf16 MFMA, NO LDS, NO BARRIERS):
// hw[r][0:32] = isd[r] * (x[r] @ W1)  (cols 30,31 auto-zero from Wt pad)
// Each wave owns 32 rows (2 m-frags); A-fragments loaded straight from x
// (lane l: row=base+(l&15), k-octet=(l>>4)*8), B-fragments from Wt (L2-hot).
// Zero-padded Wt makes the K-tail exact: A-garbage x B-zero = 0.
// ---------------------------------------------------------------------------
__global__ __launch_bounds__(256) void gemm1_mfma(const float* __restrict__ x,
                                                  const __hip_bfloat16* __restrict__ Wt,
                                                  const float* __restrict__ isd,
                                                  float* __restrict__ hw, int N) {
    const int lane = threadIdx.x & 63;
    const int wv = threadIdx.x >> 6;
    const int row0 = blockIdx.x * 128 + wv * 32;
    const int mr = lane & 15;
    const int koct = (lane >> 4) << 3;

    long long baseA[2];
#pragma unroll
    for (int m = 0; m < 2; ++m) {
        int r = min(row0 + m * 16 + mr, N - 1);   // clamp: loads stay in-bounds
        baseA[m] = (long long)r * FIN + koct;
    }
    const __hip_bfloat16* wb[2] = { Wt + mr * WTK + koct,
                                    Wt + (mr + 16) * WTK + koct };

    f32x4 acc[2][2] = {};

#pragma unroll 2
    for (int k0 = 0; k0 < 1408; k0 += 32) {       // full steps, no guards
        short8v a[2], b[2];
#pragma unroll
        for (int m = 0; m < 2; ++m) {
            const float* p = x + baseA[m] + k0;
            short8v r;
#pragma unroll
            for (int i = 0; i < 8; ++i) r[i] = bf16b(__builtin_nontemporal_load(p + i));
            a[m] = r;
        }
#pragma unroll
        for (int n = 0; n < 2; ++n) b[n] = *(const short8v*)(wb[n] + k0);
#pragma unroll
        for (int m = 0; m < 2; ++m)
#pragma unroll
            for (int n = 0; n < 2; ++n)
                acc[m][n] = __builtin_amdgcn_mfma_f32_16x16x32_bf16(a[m], b[n], acc[m][n], 0, 0, 0);
    }
    {   // tail step k0=1408 (k valid to 1432), guarded loads
        const int k0 = 1408;
        short8v a[2], b[2];
#pragma unroll
        for (int m = 0; m < 2; ++m) {
            short8v r;
#pragma unroll
            for (int i = 0; i < 8; ++i) {
                int kk = k0 + koct + i;
                r[i] = (kk < FIN) ? bf16b(x[baseA[m] + k0 + i]) : (short)0;
            }
            a[m] = r;
        }
#pragma unroll
        for (int n = 0; n < 2; ++n) b[n] = *(const short8v*)(wb[n] + k0);
#pragma unroll
        for (int m = 0; m < 2; ++m)
#pragma unroll
            for (int n = 0; n < 2; ++n)
                acc[m][n] = __builtin_amdgcn_mfma_f32_16x16x32_bf16(a[m], b[n], acc[m][n], 0, 0, 0);
    }
    // epilogue: D layout col=lane&15, row=(lane>>4)*4+r; scale by isd, stride-32 store
#pragma unroll
    for (int m = 0; m < 2; ++m)
#pragma unroll
        for (int r = 0; r < 4; ++r) {
            int grow = row0 + m * 16 + (lane >> 4) * 4 + r;
            if (grow < N) {
                float s = isd[grow];
#pragma unroll
                for (int n = 0; n < 2; ++n)
                    hw[(long long)grow * S1 + n * 16 + mr] = s * acc[m][n][r];
            }
        }
}

// ---------------------------------------------------------------------------
// Small dense transforms; reads stride SIi, writes stride SOo with zero pad
// ---------------------------------------------------------------------------
template <int FI, int SIi, int FO, int SOo>
__global__ __launch_bounds__(256) void gemm_small(const float* __restrict__ h,
                                                  const float* __restrict__ W,
                                                  const float* __restrict__ isd,
                                                  float* __restrict__ out, int N) {
    int i = blockIdx.x * blockDim.x + threadIdx.x;
    if (i >= N) return;
    float hv[FI];
#pragma unroll
    for (int k = 0; k < FI; ++k) hv[k] = h[(long long)i * SIi + k];
    float s = isd[i];
#pragma unroll
    for (int j = 0; j < SOo; ++j) {
        float a = 0.f;
        if (j < FO) {
#pragma unroll
            for (int k = 0; k < FI; ++k) a = fmaf(hv[k], W[k * FO + j], a);
            a *= s;
        }
        out[(long long)i * SOo + j] = a;
    }
}

// ---------------------------------------------------------------------------
// Propagation over CSR, float4 gathers. One wave per node; R=64/S replicas
// each fetch one full (padded) source row per step as S aligned float4s.
// hws rows pre-scaled by isd[src]:  out = EPI(isd[n]*(sum hws[src]+hws[n])+b)
// EPI: 1 = relu (padded float4 store)   2 = log_softmax (exact-width store)
// ---------------------------------------------------------------------------
template <int S, int SIi, int SOo, int FO, int EPI>
__global__ __launch_bounds__(256) void prop_kernel(const float* __restrict__ hws,
                                                   const float* __restrict__ isd,
                                                   const int* __restrict__ rowptr,
                                                   const int* __restrict__ col,
                                                   const float* __restrict__ bias,
                                                   float* __restrict__ out, int N) {
    const int R = 64 / S;
    int lane = threadIdx.x & 63;
    int li = lane & (S - 1);
    int p = lane / S;                           // replica id
    long long node = (long long)blockIdx.x * 4 + (threadIdx.x >> 6);
    if (node >= N) return;

    const bool lact = (li * 4 < SIi);           // lane owns a real quad
    f32x4 acc = {0.f, 0.f, 0.f, 0.f};
    if (p == 0 && lact) acc = *(const f32x4*)(hws + node * SIi + li * 4);  // self-loop
    int s0 = rowptr[node], s1 = rowptr[node + 1];
    for (int e0 = s0; e0 < s1; e0 += 64) {
        int e = e0 + lane;
        int ev = (e < s1) ? col[e] : 0;
        int cnt = min(64, s1 - e0);
        for (int i = 0; i * R < cnt; ++i) {
            int idx = i * R + p;
            int sj = __shfl(ev, idx, 64);
            if (idx < cnt && lact)
                acc += *(const f32x4*)(hws + (long long)sj * SIi + li * 4);
        }
    }
    // reduce replicas -> replica 0 group holds totals
#pragma unroll
    for (int o = 32; o >= S; o >>= 1) {
#pragma unroll
        for (int c = 0; c < 4; ++c) acc[c] += __shfl_xor(acc[c], o, 64);
    }
    float sn = isd[node];
    if (EPI == 1) {
        if (p == 0 && lact) {
            f32x4 r;
#pragma unroll
            for (int c = 0; c < 4; ++c) {
                int f = li * 4 + c;
                float bv = (f < FO) ? bias[f] : 0.f;
                r[c] = fmaxf(sn * acc[c] + bv, 0.f);   // pad cols -> 0
            }
            *(f32x4*)(out + node * SOo + li * 4) = r;
        }
    } else {   // log_softmax, S==2 layout (lane0: f0-3, lane1: f4-7)
        float v[4];
        float m = -1e30f;
#pragma unroll
        for (int c = 0; c < 4; ++c) {
            int f = li * 4 + c;
            v[c] = (f < FO) ? (sn * acc[c] + bias[f]) : -1e30f;
            m = fmaxf(m, v[c]);
        }
        m = fmaxf(m, __shfl_xor(m, 1, 64));
        float ss = 0.f;
#pragma unroll
        for (int c = 0; c < 4; ++c) ss += (li * 4 + c < FO) ? __expf(v[c] - m) : 0.f;
        ss += __shfl_xor(ss, 1, 64);
        if (p == 0) {
            float lg = __logf(ss);
#pragma unroll
            for (int c = 0; c < 4; ++c) {
                int f = li * 4 + c;
                if (f < FO) out[node * FO + f] = v[c] - m - lg;
            }
        }
    }
}

// ---------------------------------------------------------------------------

extern "C" void kernel_launch(void* const* d_in, const int* in_sizes, int n_in,
                              void* d_out, int out_size, void* d_ws, size_t ws_size,
                              hipStream_t stream) {
    const float* x  = (const float*)d_in[0];
    const int*   ei = (const int*)d_in[1];
    const float* W1 = (const float*)d_in[2];
    const float* b1 = (const float*)d_in[3];
    const float* W2 = (const float*)d_in[4];
    const float* b2 = (const float*)d_in[5];
    const float* W3 = (const float*)d_in[6];
    const float* b3 = (const float*)d_in[7];
    float* out = (float*)d_out;

    const int N = in_sizes[0] / FIN;
    const int E = in_sizes[1] / 2;
    const int* esrc = ei;
    const int* edst = ei + E;

    char* ws = (char*)d_ws;
    size_t off = 0;
    auto alloc = [&](size_t bytes) -> void* {
        void* p = ws + off;
        off += (bytes + 511) & ~(size_t)511;
        return p;
    };
    int NB = (N + 1023) / 1024;
    int*   ecnt   = (int*)alloc((size_t)N * 4);
    int*   cursor = (int*)alloc((size_t)N * 4);
    int*   rowptr = (int*)alloc((size_t)(N + 1) * 4);
    int*   bsum   = (int*)alloc((size_t)NB * 4);
    int*   boff   = (int*)alloc((size_t)NB * 4);
    float* isd    = (float*)alloc((size_t)N * 4);
    int*   col    = (int*)alloc((size_t)E * 4);
    __hip_bfloat16* Wt = (__hip_bfloat16*)alloc((size_t)32 * WTK * 2);
    float* hw1    = (float*)alloc((size_t)N * S1 * 4);
    float* h1     = (float*)alloc((size_t)N * S1 * 4);
    float* hw2    = (float*)alloc((size_t)N * S2 * 4);
    float* h2     = (float*)alloc((size_t)N * S2 * 4);
    float* hw3    = (float*)alloc((size_t)N * S3 * 4);

    hipMemsetAsync(ecnt, 0, (size_t)N * 4, stream);

    int eb = (E + 255) / 256;
    wt_prep<<<(32 * WTK + 255) / 256, 256, 0, stream>>>(W1, Wt);
    hist_kernel<<<eb, 256, 0, stream>>>(edst, ecnt, E);
    scanA<<<NB, 256, 0, stream>>>(ecnt, bsum, N);
    scanB<<<1, 128, 0, stream>>>(bsum, boff, rowptr, NB, N);
    scanC<<<NB, 256, 0, stream>>>(ecnt, boff, rowptr, cursor, isd, N);
    gemm1_mfma<<<(N + 127) / 128, 256, 0, stream>>>(x, Wt, isd, hw1, N);
    scatter_kernel<<<eb, 256, 0, stream>>>(esrc, edst, cursor, col, E);

    prop_kernel<8, S1, S1, F1, 1><<<(N + 3) / 4, 256, 0, stream>>>(hw1, isd, rowptr, col, b1, h1, N);
    gemm_small<F1, S1, F2, S2><<<(N + 255) / 256, 256, 0, stream>>>(h1, W2, isd, hw2, N);
    prop_kernel<4, S2, S2, F2, 1><<<(N + 3) / 4, 256, 0, stream>>>(hw2, isd, rowptr, col, b2, h2, N);
    gemm_small<F2, S2, F3, S3><<<(N + 255) / 256, 256, 0, stream>>>(h2, W3, isd, hw3, N);
    prop_kernel<2, S3, 7, F3, 2><<<(N + 3) / 4, 256, 0, stream>>>(hw3, isd, rowptr, col, b3, out, N);
}